// Round 2
// baseline (6052.233 us; speedup 1.0000x reference)
//
#include <hip/hip_runtime.h>
#include <hip/hip_bf16.h>

#define HID 128
#define ET 64          // edges (or nodes) per block
#define WO 32          // output columns per wave
#define NEDGE 800000
#define NNODE 50000
#define NGRAPH 64

__device__ __forceinline__ float silu_f(float x) {
    // x * sigmoid(x); __expf + rcp is ~1e-6 rel err, fine vs fp32 ref
    return x * __frcp_rn(1.0f + __expf(-x)) ;
}

// acc[t] += a{x,y,z,w} * w[k][o0+t] for 4 consecutive k rows (row stride HID).
// w is wave-uniform -> s_load; a* are the only VGPR operands.
__device__ __forceinline__ void gemv4(float* __restrict__ acc,
                                      float ax, float ay, float az, float aw,
                                      const float* __restrict__ w) {
#pragma unroll
    for (int t = 0; t < WO; ++t) acc[t] = fmaf(ax, w[t], acc[t]);
#pragma unroll
    for (int t = 0; t < WO; ++t) acc[t] = fmaf(ay, w[HID + t], acc[t]);
#pragma unroll
    for (int t = 0; t < WO; ++t) acc[t] = fmaf(az, w[2 * HID + t], acc[t]);
#pragma unroll
    for (int t = 0; t < WO; ++t) acc[t] = fmaf(aw, w[3 * HID + t], acc[t]);
}

// ---------------------------------------------------------------------------
// K0: zero agg_msg workspace, copy pos -> out_pos (atomics add onto it later)
// ---------------------------------------------------------------------------
__global__ __launch_bounds__(256) void init_kernel(const float* __restrict__ pos,
                                                   float* __restrict__ agg,
                                                   float* __restrict__ out_pos) {
    const int tid = blockIdx.x * blockDim.x + threadIdx.x;
    const int stride = gridDim.x * blockDim.x;
    float4* a4 = reinterpret_cast<float4*>(agg);
    const int nAgg4 = NNODE * HID / 4;  // 1.6M
    for (int i = tid; i < nAgg4; i += stride) a4[i] = make_float4(0.f, 0.f, 0.f, 0.f);
    const float4* p4 = reinterpret_cast<const float4*>(pos);
    float4* o4 = reinterpret_cast<float4*>(out_pos);
    const int nPos4 = NNODE * 3 / 4;    // 37500
    for (int i = tid; i < nPos4; i += stride) o4[i] = p4[i];
}

// ---------------------------------------------------------------------------
// K1: film = cond @ W_film + b_film   [64,128]@[128,256] -> [64,256]
// ---------------------------------------------------------------------------
__global__ __launch_bounds__(256) void film_kernel(const float* __restrict__ cond,
                                                   const float* __restrict__ Wf,
                                                   const float* __restrict__ bf,
                                                   float* __restrict__ film) {
    const int g = blockIdx.x;
    const int o = threadIdx.x;  // 0..255
    const float* __restrict__ cg = cond + g * 128;  // uniform per block -> s_load
    float acc = bf[o];
    for (int k = 0; k < 128; ++k) acc = fmaf(cg[k], Wf[k * 256 + o], acc);
    film[g * 256 + o] = acc;
}

// ---------------------------------------------------------------------------
// K2: edge kernel — msg MLP (2 layers) + coord MLP, scatter-add aggregates
// block = 256 threads = 4 waves; lane = edge within tile, wave = 32-col slice
// ---------------------------------------------------------------------------
__global__ __launch_bounds__(256) void edge_kernel(
    const float* __restrict__ h, const float* __restrict__ pos,
    const float* __restrict__ edge_attr, const int* __restrict__ eidx,
    const float* __restrict__ W1, const float* __restrict__ b1,
    const float* __restrict__ W2, const float* __restrict__ b2,
    const float* __restrict__ Wc1, const float* __restrict__ bc1,
    const float* __restrict__ Wc2,
    float* __restrict__ agg_msg, float* __restrict__ out_pos) {
    __shared__ float m_lds[ET][HID + 1];   // +1 pad: 2 lanes/bank = conflict-free
    __shared__ float cw_part[4][ET];

    const int lane = threadIdx.x & 63;
    const int wv = threadIdx.x >> 6;
    const int o0 = __builtin_amdgcn_readfirstlane(wv << 5);  // wave-uniform col base

    const int e = blockIdx.x * ET + lane;   // NEDGE % ET == 0, no guard needed
    const int ni = eidx[e];
    const int nj = eidx[NEDGE + e];

    const float pix = pos[ni * 3 + 0], piy = pos[ni * 3 + 1], piz = pos[ni * 3 + 2];
    const float pjx = pos[nj * 3 + 0], pjy = pos[nj * 3 + 1], pjz = pos[nj * 3 + 2];
    const float rx = pix - pjx, ry = piy - pjy, rz = piz - pjz;
    const float d2 = rx * rx + ry * ry + rz * rz;

    const float* __restrict__ hi = h + (size_t)ni * HID;
    const float* __restrict__ hj = h + (size_t)nj * HID;

    // ---- layer 1: silu(msg_input @ W1 + b1), K = 273 ----
    float acc[WO];
#pragma unroll
    for (int t = 0; t < WO; ++t) acc[t] = b1[o0 + t];

    for (int kb = 0; kb < HID; kb += 4) {
        const float4 a = *reinterpret_cast<const float4*>(hi + kb);
        gemv4(acc, a.x, a.y, a.z, a.w, W1 + (size_t)kb * HID + o0);
    }
    for (int kb = 0; kb < HID; kb += 4) {
        const float4 a = *reinterpret_cast<const float4*>(hj + kb);
        gemv4(acc, a.x, a.y, a.z, a.w, W1 + (size_t)(HID + kb) * HID + o0);
    }
    {   // k = 256 : dist_sq
        const float* __restrict__ w = W1 + (size_t)256 * HID + o0;
#pragma unroll
        for (int t = 0; t < WO; ++t) acc[t] = fmaf(d2, w[t], acc[t]);
    }
    {   // k = 257..272 : edge_attr
        const float* __restrict__ eae = edge_attr + (size_t)e * 16;
#pragma unroll
        for (int kb = 0; kb < 16; kb += 4) {
            const float4 a = *reinterpret_cast<const float4*>(eae + kb);
            gemv4(acc, a.x, a.y, a.z, a.w, W1 + (size_t)(257 + kb) * HID + o0);
        }
    }
#pragma unroll
    for (int t = 0; t < WO; ++t) acc[t] = silu_f(acc[t]);

    // exchange m through LDS
#pragma unroll
    for (int t = 0; t < WO; ++t) m_lds[lane][o0 + t] = acc[t];
    __syncthreads();

    // ---- layer 2: m_ij = silu(m @ W2 + b2), K = 128 ----
    float acc2[WO];
#pragma unroll
    for (int t = 0; t < WO; ++t) acc2[t] = b2[o0 + t];
    for (int kb = 0; kb < HID; kb += 4) {
        const float a0 = m_lds[lane][kb + 0];
        const float a1 = m_lds[lane][kb + 1];
        const float a2 = m_lds[lane][kb + 2];
        const float a3 = m_lds[lane][kb + 3];
        gemv4(acc2, a0, a1, a2, a3, W2 + (size_t)kb * HID + o0);
    }
#pragma unroll
    for (int t = 0; t < WO; ++t) acc2[t] = silu_f(acc2[t]);

    __syncthreads();   // all reads of m done before overwrite
#pragma unroll
    for (int t = 0; t < WO; ++t) m_lds[lane][o0 + t] = acc2[t];

    // scatter m_ij -> agg_msg (fire-and-forget atomics, overlap with rest)
    {
        float* __restrict__ am = agg_msg + (size_t)ni * HID + o0;
#pragma unroll
        for (int t = 0; t < WO; ++t) atomicAdd(am + t, acc2[t]);
    }
    __syncthreads();

    // ---- layer 3: coord_w = silu(m_ij @ Wc1 + bc1) @ Wc2, K = 128 ----
    float acc3[WO];
#pragma unroll
    for (int t = 0; t < WO; ++t) acc3[t] = bc1[o0 + t];
    for (int kb = 0; kb < HID; kb += 4) {
        const float a0 = m_lds[lane][kb + 0];
        const float a1 = m_lds[lane][kb + 1];
        const float a2 = m_lds[lane][kb + 2];
        const float a3 = m_lds[lane][kb + 3];
        gemv4(acc3, a0, a1, a2, a3, Wc1 + (size_t)kb * HID + o0);
    }
    float cw = 0.f;
#pragma unroll
    for (int t = 0; t < WO; ++t) cw += silu_f(acc3[t]) * Wc2[o0 + t];
    cw_part[wv][lane] = cw;
    __syncthreads();

    if (wv == 0) {
        const float cwf = cw_part[0][lane] + cw_part[1][lane] +
                          cw_part[2][lane] + cw_part[3][lane];
        const float s = cwf / sqrtf(d2 + 1e-8f);
        float* __restrict__ op = out_pos + (size_t)ni * 3;
        atomicAdd(op + 0, rx * s);
        atomicAdd(op + 1, ry * s);
        atomicAdd(op + 2, rz * s);
    }
}

// ---------------------------------------------------------------------------
// K3: node kernel — node MLP + FiLM + residual + LayerNorm
// ---------------------------------------------------------------------------
__global__ __launch_bounds__(256) void node_kernel(
    const float* __restrict__ h, const float* __restrict__ agg_msg,
    const float* __restrict__ film, const int* __restrict__ batch,
    const float* __restrict__ Wn1, const float* __restrict__ bn1,
    const float* __restrict__ Wn2, const float* __restrict__ bn2,
    const float* __restrict__ lng, const float* __restrict__ lnb,
    float* __restrict__ out_h) {
    __shared__ float u_lds[ET][HID + 1];
    __shared__ float red[2][4][ET];

    const int lane = threadIdx.x & 63;
    const int wv = threadIdx.x >> 6;
    const int o0 = __builtin_amdgcn_readfirstlane(wv << 5);

    const int n = blockIdx.x * ET + lane;
    const bool valid = (n < NNODE);
    const int nc = valid ? n : (NNODE - 1);

    const float* __restrict__ hr = h + (size_t)nc * HID;
    const float* __restrict__ ar = agg_msg + (size_t)nc * HID;

    // ---- layer 1: silu([h, agg] @ Wn1 + bn1), K = 256 ----
    float acc[WO];
#pragma unroll
    for (int t = 0; t < WO; ++t) acc[t] = bn1[o0 + t];
    for (int kb = 0; kb < HID; kb += 4) {
        const float4 a = *reinterpret_cast<const float4*>(hr + kb);
        gemv4(acc, a.x, a.y, a.z, a.w, Wn1 + (size_t)kb * HID + o0);
    }
    for (int kb = 0; kb < HID; kb += 4) {
        const float4 a = *reinterpret_cast<const float4*>(ar + kb);
        gemv4(acc, a.x, a.y, a.z, a.w, Wn1 + (size_t)(HID + kb) * HID + o0);
    }
#pragma unroll
    for (int t = 0; t < WO; ++t) u_lds[lane][o0 + t] = silu_f(acc[t]);
    __syncthreads();

    // ---- layer 2: hn = u @ Wn2 + bn2, K = 128 ----
    float acc2[WO];
#pragma unroll
    for (int t = 0; t < WO; ++t) acc2[t] = bn2[o0 + t];
    for (int kb = 0; kb < HID; kb += 4) {
        const float a0 = u_lds[lane][kb + 0];
        const float a1 = u_lds[lane][kb + 1];
        const float a2 = u_lds[lane][kb + 2];
        const float a3 = u_lds[lane][kb + 3];
        gemv4(acc2, a0, a1, a2, a3, Wn2 + (size_t)kb * HID + o0);
    }

    // ---- FiLM + residual ----
    const int g = batch[nc];
    const float* __restrict__ fg = film + (size_t)g * 256;
    float x[WO];
    float s1 = 0.f;
#pragma unroll
    for (int t = 0; t < WO; ++t) {
        const float gm = fg[o0 + t];
        const float bt = fg[128 + o0 + t];
        const float v = hr[o0 + t] + fmaf(gm, acc2[t], bt);
        x[t] = v;
        s1 += v;
    }
    red[0][wv][lane] = s1;
    __syncthreads();
    const float mu = (red[0][0][lane] + red[0][1][lane] +
                      red[0][2][lane] + red[0][3][lane]) * (1.f / 128.f);
    float s2 = 0.f;
#pragma unroll
    for (int t = 0; t < WO; ++t) {
        const float d = x[t] - mu;
        s2 += d * d;
    }
    red[1][wv][lane] = s2;
    __syncthreads();
    const float var = (red[1][0][lane] + red[1][1][lane] +
                       red[1][2][lane] + red[1][3][lane]) * (1.f / 128.f);
    const float rstd = 1.0f / sqrtf(var + 1e-5f);

    if (valid) {
        float* __restrict__ orow = out_h + (size_t)n * HID + o0;
#pragma unroll
        for (int t = 0; t < WO; ++t)
            orow[t] = (x[t] - mu) * rstd * lng[o0 + t] + lnb[o0 + t];
    }
}

// ---------------------------------------------------------------------------
extern "C" void kernel_launch(void* const* d_in, const int* in_sizes, int n_in,
                              void* d_out, int out_size, void* d_ws, size_t ws_size,
                              hipStream_t stream) {
    const float* h    = (const float*)d_in[0];
    const float* pos  = (const float*)d_in[1];
    const float* ea   = (const float*)d_in[2];
    const float* cond = (const float*)d_in[3];
    const int*   eidx = (const int*)d_in[4];
    const int*   batch= (const int*)d_in[5];
    const float* W1   = (const float*)d_in[6];
    const float* b1   = (const float*)d_in[7];
    const float* W2   = (const float*)d_in[8];
    const float* b2   = (const float*)d_in[9];
    const float* Wc1  = (const float*)d_in[10];
    const float* bc1  = (const float*)d_in[11];
    const float* Wc2  = (const float*)d_in[12];
    const float* Wn1  = (const float*)d_in[13];
    const float* bn1  = (const float*)d_in[14];
    const float* Wn2  = (const float*)d_in[15];
    const float* bn2  = (const float*)d_in[16];
    const float* Wf   = (const float*)d_in[17];
    const float* bf   = (const float*)d_in[18];
    const float* lng  = (const float*)d_in[19];
    const float* lnb  = (const float*)d_in[20];

    float* out_h   = (float*)d_out;                        // [N,128]
    float* out_pos = out_h + (size_t)NNODE * HID;          // [N,3]
    float* agg_msg = (float*)d_ws;                         // [N,128] scratch
    float* film    = agg_msg + (size_t)NNODE * HID;        // [64,256] scratch

    init_kernel<<<2048, 256, 0, stream>>>(pos, agg_msg, out_pos);
    film_kernel<<<NGRAPH, 256, 0, stream>>>(cond, Wf, bf, film);
    edge_kernel<<<NEDGE / ET, 256, 0, stream>>>(h, pos, ea, eidx,
                                                W1, b1, W2, b2, Wc1, bc1, Wc2,
                                                agg_msg, out_pos);
    node_kernel<<<(NNODE + ET - 1) / ET, 256, 0, stream>>>(h, agg_msg, film, batch,
                                                           Wn1, bn1, Wn2, bn2,
                                                           lng, lnb, out_h);
}